// Round 9
// baseline (5138.243 us; speedup 1.0000x reference)
//
#include <hip/hip_runtime.h>
#include <math.h>
#include <stdint.h>

#define HIDDEN 2048
#define TSTEPS 1024
#define NWG 256
#define TPB 512
#define UPW 8              // hidden units per WG
#define CPT 16             // columns per thread
#define CHUNK_QW 6         // tagged qwords per producer chunk (16 halves + tags)
#define STEP_QW (NWG * CHUNK_QW)   // 1536 qwords per step slot
#define GO_STRIDE 32       // ints per line (128 B)
#define FLAG_STRIDE 32
#define NXCD 8

__device__ __forceinline__ float sigmoidf_(float x) { return 1.0f / (1.0f + __expf(-x)); }

// sc0 load: bypass L1, hit the XCD-shared L2 (intra-XCD coherence point for
// plain stores). gfx950 spelling is sc0 (glc does not assemble).
__device__ __forceinline__ int load_go_sc0(const int* p) {
    int v;
    asm volatile("global_load_dword %0, %1, off sc0\n\t"
                 "s_waitcnt vmcnt(0)"
                 : "=v"(v) : "v"(p) : "memory");
    return v;
}

// ============ primary (round-9): tagged h + per-XCD relay with L2-local go ============
__global__ __launch_bounds__(TPB, 2)
void lstm_v9(const float* __restrict__ features,
             const float* __restrict__ pc,
             const float* __restrict__ W_ih,
             const float* __restrict__ W_hh,
             const float* __restrict__ b_ih,
             const float* __restrict__ b_hh,
             const float* __restrict__ W_fc,
             const float* __restrict__ b_fc,
             float* __restrict__ out,
             int*      __restrict__ elect,    // NXCD lines, memset 0
             int*      __restrict__ go_l,     // NXCD lines, memset 0 (L2-local go)
             int*      __restrict__ go_glob,  // 64 lines, memset 0 (agent backstop)
             uint64_t* __restrict__ hh)       // (TSTEPS+1)*STEP_QW qwords, memset 0
{
    const int b    = blockIdx.x;
    const int t    = threadIdx.x;
    const int lane = t & 63;
    const int wave = t >> 6;
    const int g    = t & 3;        // gate block 0..3 (i,f,g,o)
    const int cc   = t >> 2;       // column-chunk 0..127
    const int col0 = cc * CPT;

    // Invalidate L1/L2 across graph replays before any cached read of ws.
    __builtin_amdgcn_fence(__ATOMIC_ACQUIRE, "agent");

    // which XCD is this WG on? (all waves of a WG share one CU -> one XCD)
    uint32_t xcdreg;
    asm volatile("s_getreg_b32 %0, hwreg(HW_REG_XCC_ID)" : "=s"(xcdreg));
    const int myxcd = (int)(xcdreg & (NXCD - 1));

    __shared__ float pc_sh[2 * TSTEPS];
    __shared__ float red[8 * 32];
    __shared__ float outred[16];
    __shared__ int   ls_relay;

    // elect exactly one relay WG per XCD (one-time agent CAS)
    if (t == 0) {
        int expected = 0;
        const bool won = __hip_atomic_compare_exchange_strong(
            elect + (size_t)myxcd * GO_STRIDE, &expected, 1,
            __ATOMIC_RELAXED, __ATOMIC_RELAXED, __HIP_MEMORY_SCOPE_AGENT);
        ls_relay = won ? 1 : 0;
    }

    {   // point cloud -> LDS
        const float4* p4 = reinterpret_cast<const float4*>(pc);
        reinterpret_cast<float4*>(pc_sh)[t] = p4[t];
    }

    // W_hh slice -> registers
    float w[UPW][CPT];
    {
        const int baserow = g * HIDDEN + b * UPW;
        #pragma unroll
        for (int ji = 0; ji < UPW; ++ji) {
            const float4* src = reinterpret_cast<const float4*>(
                W_hh + (size_t)(baserow + ji) * HIDDEN + col0);
            float4 a0 = src[0], a1 = src[1], a2 = src[2], a3 = src[3];
            w[ji][0]  = a0.x; w[ji][1]  = a0.y; w[ji][2]  = a0.z; w[ji][3]  = a0.w;
            w[ji][4]  = a1.x; w[ji][5]  = a1.y; w[ji][6]  = a1.z; w[ji][7]  = a1.w;
            w[ji][8]  = a2.x; w[ji][9]  = a2.y; w[ji][10] = a2.z; w[ji][11] = a2.w;
            w[ji][12] = a3.x; w[ji][13] = a3.y; w[ji][14] = a3.z; w[ji][15] = a3.w;
        }
    }

    float bias_r = 0.0f, wi0_r = 0.0f, wi1_r = 0.0f, creg = 0.0f;
    if (wave == 0) {
        const int l   = lane & 31;
        const int row = (l >> 3) * HIDDEN + b * UPW + (l & 7);
        bias_r = b_ih[row] + b_hh[row];
        wi0_r  = W_ih[row * 2 + 0];
        wi1_r  = W_ih[row * 2 + 1];
    }
    __syncthreads();
    const bool isrelay = (ls_relay != 0);

    for (int s = 0; s < TSTEPS; ++s) {
        const int rot = (s >= 1) && (b == ((s - 1) & 255));

        // ---- load h_s slice (plain cached, tag-validated; v8-proven) ----
        float hr[CPT];
        if (s == 0) {
            #pragma unroll
            for (int k = 0; k < CPT; k += 4) {
                float4 hv = *reinterpret_cast<const float4*>(features + col0 + k);
                hr[k] = hv.x; hr[k + 1] = hv.y; hr[k + 2] = hv.z; hr[k + 3] = hv.w;
            }
        } else {
            const uint64_t* qp = hh + (size_t)s * STEP_QW + (size_t)(cc * 2) * CHUNK_QW;
            const uint32_t tagexp = (uint32_t)s;
            #pragma unroll
            for (int c2 = 0; c2 < 2; ++c2) {
                uint64_t q[CHUNK_QW];
                const ulonglong2* qp2 = reinterpret_cast<const ulonglong2*>(qp + c2 * CHUNK_QW);
                ulonglong2 u0 = qp2[0], u1 = qp2[1], u2 = qp2[2];
                q[0] = u0.x; q[1] = u0.y; q[2] = u1.x;
                q[3] = u1.y; q[4] = u2.x; q[5] = u2.y;
                #pragma unroll
                for (int j = 0; j < CHUNK_QW; ++j) {
                    if ((uint32_t)(q[j] >> 48) != tagexp) {
                        do {
                            q[j] = __hip_atomic_load(qp + c2 * CHUNK_QW + j,
                                                     __ATOMIC_RELAXED, __HIP_MEMORY_SCOPE_AGENT);
                        } while ((uint32_t)(q[j] >> 48) != tagexp);
                    }
                }
                uint32_t H[3 * CHUNK_QW];
                #pragma unroll
                for (int j = 0; j < CHUNK_QW; ++j) {
                    H[3 * j + 0] = (uint32_t)(q[j] >> 32) & 0xFFFFu;
                    H[3 * j + 1] = (uint32_t)(q[j] >> 16) & 0xFFFFu;
                    H[3 * j + 2] = (uint32_t)(q[j] >>  0) & 0xFFFFu;
                }
                #pragma unroll
                for (int i = 0; i < 8; ++i) {
                    hr[c2 * 8 + i] = __uint_as_float(H[2 * i] | (H[2 * i + 1] << 16));
                }
            }
        }

        // ---- FMA phase ----
        float acc[UPW];
        #pragma unroll
        for (int ji = 0; ji < UPW; ++ji) acc[ji] = 0.0f;
        #pragma unroll
        for (int k = 0; k < CPT; ++k) {
            #pragma unroll
            for (int ji = 0; ji < UPW; ++ji) acc[ji] += w[ji][k] * hr[k];
        }
        #pragma unroll
        for (int m = 4; m < 64; m <<= 1) {
            #pragma unroll
            for (int ji = 0; ji < UPW; ++ji) acc[ji] += __shfl_xor(acc[ji], m);
        }
        if (lane < 4) {
            #pragma unroll
            for (int ji = 0; ji < UPW; ++ji) red[wave * 32 + lane * 8 + ji] = acc[ji];
        }

        // fc partials for out[s-1] (rotating WG; rides barrier (a))
        if (rot) {
            float po0 = 0.0f, po1 = 0.0f;
            #pragma unroll
            for (int k = 0; k < CPT; ++k) {
                po0 += hr[k] * W_fc[col0 + k];
                po1 += hr[k] * W_fc[HIDDEN + col0 + k];
            }
            #pragma unroll
            for (int m = 1; m < 64; m <<= 1) {
                po0 += __shfl_xor(po0, m);
                po1 += __shfl_xor(po1, m);
            }
            if (lane == 0) { outred[wave * 2 + 0] = po0; outred[wave * 2 + 1] = po1; }
        }
        __syncthreads();   // (a)

        const size_t pubbase = (size_t)(s + 1) * STEP_QW;

        if (wave == 0) {
            // final reduce + gates
            const int l = lane & 31;
            float sum = 0.0f;
            #pragma unroll
            for (int ww = 0; ww < 8; ++ww) sum += red[ww * 32 + l];
            const float x0 = pc_sh[2 * s], x1 = pc_sh[2 * s + 1];
            const float gate = sum + bias_r + wi0_r * x0 + wi1_r * x1;
            const float iv = __shfl(gate, (lane & 7));
            const float fv = __shfl(gate, 8 + (lane & 7));
            const float gv = __shfl(gate, 16 + (lane & 7));
            const float ov = __shfl(gate, 24 + (lane & 7));
            const float cnew = sigmoidf_(fv) * creg + sigmoidf_(iv) * tanhf(gv);
            const float hnew = sigmoidf_(ov) * tanhf(cnew);
            creg = cnew;
            const uint32_t hb = __float_as_uint(hnew);

            // self-validating publish (no ack, no flag)
            uint64_t v = ((uint64_t)(uint32_t)(s + 1)) << 48;
            #pragma unroll
            for (int i = 0; i < 3; ++i) {
                const int m  = 3 * lane + i;
                const int mc = (m < 16) ? m : 15;
                const uint32_t bits = __shfl(hb, mc >> 1);
                const uint32_t half = (mc & 1) ? (bits >> 16) : (bits & 0xFFFFu);
                if (m < 16) v |= (uint64_t)half << (32 - 16 * i);
            }
            if (lane < CHUNK_QW) {
                __hip_atomic_store(hh + pubbase + (size_t)b * CHUNK_QW + lane,
                                   v, __ATOMIC_RELAXED, __HIP_MEMORY_SCOPE_AGENT);
            }
        }

        // ---- relay: elected WG's wave 7 (overlaps gate compute) ----
        if (isrelay && wave == 7) {
            const uint32_t tagexp = (uint32_t)(s + 1);
            const int l4 = lane * 4;
            const uint64_t* p0 = hh + pubbase + (size_t)(l4 + 0) * CHUNK_QW + 5;
            const uint64_t* p1 = hh + pubbase + (size_t)(l4 + 1) * CHUNK_QW + 5;
            const uint64_t* p2 = hh + pubbase + (size_t)(l4 + 2) * CHUNK_QW + 5;
            const uint64_t* p3 = hh + pubbase + (size_t)(l4 + 3) * CHUNK_QW + 5;
            for (;;) {
                const uint64_t q0 = __hip_atomic_load(p0, __ATOMIC_RELAXED, __HIP_MEMORY_SCOPE_AGENT);
                const uint64_t q1 = __hip_atomic_load(p1, __ATOMIC_RELAXED, __HIP_MEMORY_SCOPE_AGENT);
                const uint64_t q2 = __hip_atomic_load(p2, __ATOMIC_RELAXED, __HIP_MEMORY_SCOPE_AGENT);
                const uint64_t q3 = __hip_atomic_load(p3, __ATOMIC_RELAXED, __HIP_MEMORY_SCOPE_AGENT);
                const bool ok = ((uint32_t)(q0 >> 48) == tagexp) &
                                ((uint32_t)(q1 >> 48) == tagexp) &
                                ((uint32_t)(q2 >> 48) == tagexp) &
                                ((uint32_t)(q3 >> 48) == tagexp);
                if (__all(ok)) break;
            }
            // L2-local go: plain store lands in this XCD's L2 (write-back,
            // updates the line consumers sc0-read).
            if (lane == 0) {
                go_l[(size_t)myxcd * GO_STRIDE] = s + 1;
                asm volatile("" ::: "memory");
            }
            // agent backstop lines (v6 topology: 1 writer, <=4 pollers... rarely read)
            __hip_atomic_store(go_glob + (size_t)lane * GO_STRIDE, s + 1,
                               __ATOMIC_RELAXED, __HIP_MEMORY_SCOPE_AGENT);
        }

        // out[s-1] final sum
        if (rot && t == 64) {
            float o0 = 0.0f, o1 = 0.0f;
            #pragma unroll
            for (int ww = 0; ww < 8; ++ww) { o0 += outred[ww * 2]; o1 += outred[ww * 2 + 1]; }
            out[(s - 1) * 2 + 0] = 0.25f * o0 + b_fc[0];
            out[(s - 1) * 2 + 1] = 0.25f * o1 + b_fc[1];
        }

        // hybrid go gate: sc0 poll of local L2 line; every 16th miss check the
        // agent backstop (degrades to ~r6 behavior if sc0 semantics differ).
        if (t == 0) {
            const int* lp = go_l + (size_t)myxcd * GO_STRIDE;
            const int* gp = go_glob + (size_t)(b >> 2) * GO_STRIDE;
            int it = 0;
            for (;;) {
                if (load_go_sc0(lp) >= s + 1) break;
                if ((++it & 15) == 0) {
                    if (__hip_atomic_load(gp, __ATOMIC_RELAXED,
                                          __HIP_MEMORY_SCOPE_AGENT) >= s + 1) break;
                }
            }
        }
        __syncthreads();   // (b)
    }

    // ---- epilogue: out[T-1] = fc(h_T); (T-1)&255 = 255 ----
    if (b == NWG - 1) {
        const uint64_t* qp = hh + (size_t)TSTEPS * STEP_QW + (size_t)(cc * 2) * CHUNK_QW;
        const uint32_t tagexp = (uint32_t)TSTEPS;
        float hv[CPT];
        #pragma unroll
        for (int c2 = 0; c2 < 2; ++c2) {
            uint64_t q[CHUNK_QW];
            const ulonglong2* qp2 = reinterpret_cast<const ulonglong2*>(qp + c2 * CHUNK_QW);
            ulonglong2 u0 = qp2[0], u1 = qp2[1], u2 = qp2[2];
            q[0] = u0.x; q[1] = u0.y; q[2] = u1.x;
            q[3] = u1.y; q[4] = u2.x; q[5] = u2.y;
            #pragma unroll
            for (int j = 0; j < CHUNK_QW; ++j) {
                if ((uint32_t)(q[j] >> 48) != tagexp) {
                    do {
                        q[j] = __hip_atomic_load(qp + c2 * CHUNK_QW + j,
                                                 __ATOMIC_RELAXED, __HIP_MEMORY_SCOPE_AGENT);
                    } while ((uint32_t)(q[j] >> 48) != tagexp);
                }
            }
            uint32_t H[3 * CHUNK_QW];
            #pragma unroll
            for (int j = 0; j < CHUNK_QW; ++j) {
                H[3 * j + 0] = (uint32_t)(q[j] >> 32) & 0xFFFFu;
                H[3 * j + 1] = (uint32_t)(q[j] >> 16) & 0xFFFFu;
                H[3 * j + 2] = (uint32_t)(q[j] >>  0) & 0xFFFFu;
            }
            #pragma unroll
            for (int i = 0; i < 8; ++i) {
                hv[c2 * 8 + i] = __uint_as_float(H[2 * i] | (H[2 * i + 1] << 16));
            }
        }
        float po0 = 0.0f, po1 = 0.0f;
        #pragma unroll
        for (int k = 0; k < CPT; ++k) {
            po0 += hv[k] * W_fc[col0 + k];
            po1 += hv[k] * W_fc[HIDDEN + col0 + k];
        }
        #pragma unroll
        for (int m = 1; m < 64; m <<= 1) {
            po0 += __shfl_xor(po0, m);
            po1 += __shfl_xor(po1, m);
        }
        if (lane == 0) { outred[wave * 2 + 0] = po0; outred[wave * 2 + 1] = po1; }
        __syncthreads();
        if (t == 0) {
            float o0 = 0.0f, o1 = 0.0f;
            #pragma unroll
            for (int ww = 0; ww < 8; ++ww) { o0 += outred[ww * 2]; o1 += outred[ww * 2 + 1]; }
            out[(TSTEPS - 1) * 2 + 0] = 0.25f * o0 + b_fc[0];
            out[(TSTEPS - 1) * 2 + 1] = 0.25f * o1 + b_fc[1];
        }
    }
}

// ===================== fallback: round-6 kernel (3595 us, needs only ~40 KB + 8.4 MB... small path) =====================
__global__ __launch_bounds__(TPB, 2)
void lstm_v6(const float* __restrict__ features,
             const float* __restrict__ pc,
             const float* __restrict__ W_ih,
             const float* __restrict__ W_hh,
             const float* __restrict__ b_ih,
             const float* __restrict__ b_hh,
             const float* __restrict__ W_fc,
             const float* __restrict__ b_fc,
             float* __restrict__ out,
             int*   __restrict__ flags,
             int*   __restrict__ go,
             float* __restrict__ hhist)
{
    const int b    = blockIdx.x;
    const int t    = threadIdx.x;
    const int lane = t & 63;
    const int wave = t >> 6;
    __builtin_amdgcn_fence(__ATOMIC_ACQUIRE, "agent");
    const int g    = t & 3;
    const int cc   = t >> 2;
    const int col0 = cc * CPT;
    const bool watcher = (b == NWG - 1) && (wave == 0);

    __shared__ float pc_sh[2 * TSTEPS];
    __shared__ float red[8 * 32];
    __shared__ float outred[16];

    {
        const float4* p4 = reinterpret_cast<const float4*>(pc);
        reinterpret_cast<float4*>(pc_sh)[t] = p4[t];
    }
    float w[UPW][CPT];
    {
        const int baserow = g * HIDDEN + b * UPW;
        #pragma unroll
        for (int ji = 0; ji < UPW; ++ji) {
            const float4* src = reinterpret_cast<const float4*>(
                W_hh + (size_t)(baserow + ji) * HIDDEN + col0);
            float4 a0 = src[0], a1 = src[1], a2 = src[2], a3 = src[3];
            w[ji][0]  = a0.x; w[ji][1]  = a0.y; w[ji][2]  = a0.z; w[ji][3]  = a0.w;
            w[ji][4]  = a1.x; w[ji][5]  = a1.y; w[ji][6]  = a1.z; w[ji][7]  = a1.w;
            w[ji][8]  = a2.x; w[ji][9]  = a2.y; w[ji][10] = a2.z; w[ji][11] = a2.w;
            w[ji][12] = a3.x; w[ji][13] = a3.y; w[ji][14] = a3.z; w[ji][15] = a3.w;
        }
    }
    float bias_r = 0.0f, wi0_r = 0.0f, wi1_r = 0.0f, creg = 0.0f;
    if (wave == 0) {
        const int l   = lane & 31;
        const int row = (l >> 3) * HIDDEN + b * UPW + (l & 7);
        bias_r = b_ih[row] + b_hh[row];
        wi0_r  = W_ih[row * 2 + 0];
        wi1_r  = W_ih[row * 2 + 1];
    }
    __syncthreads();

    for (int s = 0; s < TSTEPS; ++s) {
        const int rot = (s >= 1) && (b == ((s - 1) & 255));
        const float* hsrc = (s == 0) ? features : (hhist + (size_t)s * HIDDEN);
        float hr[CPT];
        #pragma unroll
        for (int k = 0; k < CPT; k += 4) {
            float4 hv = *reinterpret_cast<const float4*>(hsrc + col0 + k);
            hr[k] = hv.x; hr[k + 1] = hv.y; hr[k + 2] = hv.z; hr[k + 3] = hv.w;
        }
        float acc[UPW];
        #pragma unroll
        for (int ji = 0; ji < UPW; ++ji) acc[ji] = 0.0f;
        #pragma unroll
        for (int k = 0; k < CPT; ++k) {
            #pragma unroll
            for (int ji = 0; ji < UPW; ++ji) acc[ji] += w[ji][k] * hr[k];
        }
        #pragma unroll
        for (int m = 4; m < 64; m <<= 1) {
            #pragma unroll
            for (int ji = 0; ji < UPW; ++ji) acc[ji] += __shfl_xor(acc[ji], m);
        }
        if (lane < 4) {
            #pragma unroll
            for (int ji = 0; ji < UPW; ++ji) red[wave * 32 + lane * 8 + ji] = acc[ji];
        }
        if (rot) {
            float po0 = 0.0f, po1 = 0.0f;
            #pragma unroll
            for (int k = 0; k < CPT; ++k) {
                po0 += hr[k] * W_fc[col0 + k];
                po1 += hr[k] * W_fc[HIDDEN + col0 + k];
            }
            #pragma unroll
            for (int m = 1; m < 64; m <<= 1) {
                po0 += __shfl_xor(po0, m);
                po1 += __shfl_xor(po1, m);
            }
            if (lane == 0) { outred[wave * 2 + 0] = po0; outred[wave * 2 + 1] = po1; }
        }
        __syncthreads();

        if (wave == 0) {
            const int l = lane & 31;
            float sum = 0.0f;
            #pragma unroll
            for (int ww = 0; ww < 8; ++ww) sum += red[ww * 32 + l];
            const float x0 = pc_sh[2 * s], x1 = pc_sh[2 * s + 1];
            const float gate = sum + bias_r + wi0_r * x0 + wi1_r * x1;
            const float iv = __shfl(gate, (lane & 7));
            const float fv = __shfl(gate, 8 + (lane & 7));
            const float gv = __shfl(gate, 16 + (lane & 7));
            const float ov = __shfl(gate, 24 + (lane & 7));
            const float cnew = sigmoidf_(fv) * creg + sigmoidf_(iv) * tanhf(gv);
            const float hnew = sigmoidf_(ov) * tanhf(cnew);
            creg = cnew;
            const uint32_t hb = __float_as_uint(hnew);
            const uint32_t lo = __shfl(hb, 2 * (lane & 3));
            const uint32_t hi = __shfl(hb, 2 * (lane & 3) + 1);
            if (lane < 4) {
                const uint64_t qv = (uint64_t)lo | ((uint64_t)hi << 32);
                uint64_t* dst = reinterpret_cast<uint64_t*>(
                    hhist + (size_t)(s + 1) * HIDDEN + b * UPW) + lane;
                __hip_atomic_store(dst, qv, __ATOMIC_RELAXED, __HIP_MEMORY_SCOPE_AGENT);
            }
            asm volatile("s_waitcnt vmcnt(0)" ::: "memory");
            if (lane == 0) {
                __hip_atomic_store(flags + (size_t)b * FLAG_STRIDE, s + 1,
                                   __ATOMIC_RELAXED, __HIP_MEMORY_SCOPE_AGENT);
            }
        }
        if (rot && t == 64) {
            float o0 = 0.0f, o1 = 0.0f;
            #pragma unroll
            for (int ww = 0; ww < 8; ++ww) { o0 += outred[ww * 2]; o1 += outred[ww * 2 + 1]; }
            out[(s - 1) * 2 + 0] = 0.25f * o0 + b_fc[0];
            out[(s - 1) * 2 + 1] = 0.25f * o1 + b_fc[1];
        }
        if (watcher) {
            const int l4 = lane * 4;
            const int* f0p = flags + (size_t)(l4 + 0) * FLAG_STRIDE;
            const int* f1p = flags + (size_t)(l4 + 1) * FLAG_STRIDE;
            const int* f2p = flags + (size_t)(l4 + 2) * FLAG_STRIDE;
            const int* f3p = flags + (size_t)(l4 + 3) * FLAG_STRIDE;
            for (;;) {
                const int f0 = __hip_atomic_load(f0p, __ATOMIC_RELAXED, __HIP_MEMORY_SCOPE_AGENT);
                const int f1 = __hip_atomic_load(f1p, __ATOMIC_RELAXED, __HIP_MEMORY_SCOPE_AGENT);
                const int f2 = __hip_atomic_load(f2p, __ATOMIC_RELAXED, __HIP_MEMORY_SCOPE_AGENT);
                const int f3 = __hip_atomic_load(f3p, __ATOMIC_RELAXED, __HIP_MEMORY_SCOPE_AGENT);
                const bool ok = (f0 >= s + 1) & (f1 >= s + 1) & (f2 >= s + 1) & (f3 >= s + 1);
                if (__all(ok)) break;
            }
            __hip_atomic_store(go + (size_t)lane * GO_STRIDE, s + 1,
                               __ATOMIC_RELAXED, __HIP_MEMORY_SCOPE_AGENT);
        }
        if (t == 0 && b != NWG - 1) {
            const int* gop = go + (size_t)(b >> 2) * GO_STRIDE;
            while (__hip_atomic_load(gop, __ATOMIC_RELAXED,
                                     __HIP_MEMORY_SCOPE_AGENT) < s + 1) {}
        }
        __syncthreads();
    }

    if (b == ((TSTEPS - 1) & 255)) {
        const float* hsrc = hhist + (size_t)TSTEPS * HIDDEN;
        float po0 = 0.0f, po1 = 0.0f;
        #pragma unroll
        for (int k = 0; k < CPT; ++k) {
            const float hv = hsrc[col0 + k];
            po0 += hv * W_fc[col0 + k];
            po1 += hv * W_fc[HIDDEN + col0 + k];
        }
        #pragma unroll
        for (int m = 1; m < 64; m <<= 1) {
            po0 += __shfl_xor(po0, m);
            po1 += __shfl_xor(po1, m);
        }
        if (lane == 0) { outred[wave * 2 + 0] = po0; outred[wave * 2 + 1] = po1; }
        __syncthreads();
        if (t == 0) {
            float o0 = 0.0f, o1 = 0.0f;
            #pragma unroll
            for (int ww = 0; ww < 8; ++ww) { o0 += outred[ww * 2]; o1 += outred[ww * 2 + 1]; }
            out[(TSTEPS - 1) * 2 + 0] = 0.25f * o0 + b_fc[0];
            out[(TSTEPS - 1) * 2 + 1] = 0.25f * o1 + b_fc[1];
        }
    }
}

extern "C" void kernel_launch(void* const* d_in, const int* in_sizes, int n_in,
                              void* d_out, int out_size, void* d_ws, size_t ws_size,
                              hipStream_t stream) {
    const float* features = (const float*)d_in[0];
    const float* pc       = (const float*)d_in[1];
    const float* W_ih     = (const float*)d_in[2];
    const float* W_hh     = (const float*)d_in[3];
    const float* b_ih     = (const float*)d_in[4];
    const float* b_hh     = (const float*)d_in[5];
    const float* W_fc     = (const float*)d_in[6];
    const float* b_fc     = (const float*)d_in[7];
    float* out = (float*)d_out;

    const size_t elect_bytes = (size_t)NXCD * GO_STRIDE * sizeof(int);   // 1 KB
    const size_t gol_bytes   = (size_t)NXCD * GO_STRIDE * sizeof(int);   // 1 KB
    const size_t gog_bytes   = (size_t)64 * GO_STRIDE * sizeof(int);     // 8 KB
    const size_t hh_off      = 16384;                                    // 16 KB (aligned)
    const size_t hh_bytes    = (size_t)(TSTEPS + 1) * STEP_QW * sizeof(uint64_t);  // ~12.6 MB
    const size_t need_v9     = hh_off + hh_bytes;

    if (ws_size >= need_v9) {
        int*      elect = (int*)d_ws;
        int*      go_l  = (int*)((char*)d_ws + elect_bytes);
        int*      go_g  = (int*)((char*)d_ws + elect_bytes + gol_bytes);
        uint64_t* hh    = (uint64_t*)((char*)d_ws + hh_off);
        // all sync state + tags cleared every call (graph replays don't re-poison ws)
        hipMemsetAsync(d_ws, 0, need_v9, stream);
        hipLaunchKernelGGL(lstm_v9, dim3(NWG), dim3(TPB), 0, stream,
                           features, pc, W_ih, W_hh, b_ih, b_hh, W_fc, b_fc,
                           out, elect, go_l, go_g, hh);
    } else {
        const size_t flags_bytes = (size_t)NWG * FLAG_STRIDE * sizeof(int);  // 32 KB
        const size_t go_bytes    = (size_t)64 * GO_STRIDE * sizeof(int);     //  8 KB
        const size_t hhf_off     = flags_bytes + go_bytes;                   // 40 KB
        int*   flags = (int*)d_ws;
        int*   go    = (int*)((char*)d_ws + flags_bytes);
        float* hhist = (float*)((char*)d_ws + hhf_off);
        hipMemsetAsync(d_ws, 0, hhf_off, stream);
        hipLaunchKernelGGL(lstm_v6, dim3(NWG), dim3(TPB), 0, stream,
                           features, pc, W_ih, W_hh, b_ih, b_hh, W_fc, b_fc,
                           out, flags, go, hhist);
    }
}

// Round 10
// 3614.193 us; speedup vs baseline: 1.4217x; 1.4217x over previous
//
#include <hip/hip_runtime.h>
#include <math.h>
#include <stdint.h>

#define HIDDEN 2048
#define TSTEPS 1024
#define NWG 256
#define TPB 512
#define UPW 8           // hidden units per WG
#define CPT 16          // columns per thread
#define FLAG_STRIDE 32  // ints per flag/go line (128 B)
#define GO_STRIDE 32

__device__ __forceinline__ float sigmoidf_(float x) { return 1.0f / (1.0f + __expf(-x)); }

// v10 = v6 protocol (fp32 hhist + ack + flag -> watcher -> go), barrier-less step loop:
//  - ONE __syncthreads per step; the go-gate orders the step transition causally
//    (red[] writes for s+1 require go(s+1) which requires this WG's flag(s+1)
//    which wave 0 stores only after reading red[] at step s).
//  - all threads poll go (wave-uniform address = 1 request/wave); h loads issue
//    immediately on go arrival, no t0->barrier relay.
//  - watcher = WG 255 wave 7 (starts at barrier (a), overlaps gate compute),
//    signals its own WG via LDS flag (no self-sync through the IF).
__global__ __launch_bounds__(TPB, 2)
void lstm_v10(const float* __restrict__ features,
              const float* __restrict__ pc,
              const float* __restrict__ W_ih,
              const float* __restrict__ W_hh,
              const float* __restrict__ b_ih,
              const float* __restrict__ b_hh,
              const float* __restrict__ W_fc,
              const float* __restrict__ b_fc,
              float* __restrict__ out,
              int*   __restrict__ flags,   // NWG lines x FLAG_STRIDE ints, memset 0
              int*   __restrict__ go,      // 64 lines x GO_STRIDE ints, memset 0
              float* __restrict__ hhist)   // (TSTEPS+1)*HIDDEN floats, slot s = h_s
{
    const int b    = blockIdx.x;
    const int t    = threadIdx.x;
    const int lane = t & 63;
    const int wave = t >> 6;
    const int g    = t & 3;        // gate block 0..3 (i,f,g,o)
    const int cc   = t >> 2;       // column-chunk 0..127
    const int col0 = cc * CPT;
    const bool isw255 = (b == NWG - 1);

    // Invalidate L1/L2 so plain cached reads of hhist can't see stale lines
    // from a previous graph replay.
    __builtin_amdgcn_fence(__ATOMIC_ACQUIRE, "agent");

    __shared__ float pc_sh[2 * TSTEPS];
    __shared__ float red[8 * 32];
    __shared__ float outred[16];
    __shared__ int   ls_go;        // WG 255 self-gate (LDS, reset every launch)

    if (t == 0) ls_go = 0;

    {   // point cloud -> LDS
        const float4* p4 = reinterpret_cast<const float4*>(pc);
        reinterpret_cast<float4*>(pc_sh)[t] = p4[t];
    }

    // W_hh slice -> registers: w[ji][k] = W_hh[g*2048 + b*8 + ji][col0 + k]
    float w[UPW][CPT];
    {
        const int baserow = g * HIDDEN + b * UPW;
        #pragma unroll
        for (int ji = 0; ji < UPW; ++ji) {
            const float4* src = reinterpret_cast<const float4*>(
                W_hh + (size_t)(baserow + ji) * HIDDEN + col0);
            float4 a0 = src[0], a1 = src[1], a2 = src[2], a3 = src[3];
            w[ji][0]  = a0.x; w[ji][1]  = a0.y; w[ji][2]  = a0.z; w[ji][3]  = a0.w;
            w[ji][4]  = a1.x; w[ji][5]  = a1.y; w[ji][6]  = a1.z; w[ji][7]  = a1.w;
            w[ji][8]  = a2.x; w[ji][9]  = a2.y; w[ji][10] = a2.z; w[ji][11] = a2.w;
            w[ji][12] = a3.x; w[ji][13] = a3.y; w[ji][14] = a3.z; w[ji][15] = a3.w;
        }
    }

    // per-row constants + cell state for wave 0 (row id l = lane&31: gate = l>>3, unit = l&7)
    float bias_r = 0.0f, wi0_r = 0.0f, wi1_r = 0.0f, creg = 0.0f;
    if (wave == 0) {
        const int l   = lane & 31;
        const int row = (l >> 3) * HIDDEN + b * UPW + (l & 7);
        bias_r = b_ih[row] + b_hh[row];
        wi0_r  = W_ih[row * 2 + 0];
        wi1_r  = W_ih[row * 2 + 1];
    }
    __syncthreads();   // covers pc_sh staging + ls_go init

    const int* gop = go + (size_t)(b >> 2) * GO_STRIDE;

    // ---- recurrence: ONE barrier per step ----
    for (int s = 0; s < TSTEPS; ++s) {
        const int rot = (s >= 1) && (b == ((s - 1) & 255));   // this WG emits out[s-1]

        // gate + load h_s
        float hr[CPT];
        if (s == 0) {
            #pragma unroll
            for (int k = 0; k < CPT; k += 4) {
                float4 hv = *reinterpret_cast<const float4*>(features + col0 + k);
                hr[k] = hv.x; hr[k + 1] = hv.y; hr[k + 2] = hv.z; hr[k + 3] = hv.w;
            }
        } else {
            if (isw255) {
                // self-gate via LDS flag set by wave 7's watcher at step s-1
                while (__hip_atomic_load(&ls_go, __ATOMIC_RELAXED,
                                         __HIP_MEMORY_SCOPE_WORKGROUP) < s) {}
            } else {
                // wave-uniform poll: 1 request/wave/round, fan-in 32 req/line
                while (__hip_atomic_load(gop, __ATOMIC_RELAXED,
                                         __HIP_MEMORY_SCOPE_AGENT) < s) {}
            }
            const float* hsrc = hhist + (size_t)s * HIDDEN;
            #pragma unroll
            for (int k = 0; k < CPT; k += 4) {
                float4 hv = *reinterpret_cast<const float4*>(hsrc + col0 + k);
                hr[k] = hv.x; hr[k + 1] = hv.y; hr[k + 2] = hv.z; hr[k + 3] = hv.w;
            }
        }

        // FMA phase
        float acc[UPW];
        #pragma unroll
        for (int ji = 0; ji < UPW; ++ji) acc[ji] = 0.0f;
        #pragma unroll
        for (int k = 0; k < CPT; ++k) {
            #pragma unroll
            for (int ji = 0; ji < UPW; ++ji) acc[ji] += w[ji][k] * hr[k];
        }
        #pragma unroll
        for (int m = 4; m < 64; m <<= 1) {
            #pragma unroll
            for (int ji = 0; ji < UPW; ++ji) acc[ji] += __shfl_xor(acc[ji], m);
        }
        if (lane < 4) {
            #pragma unroll
            for (int ji = 0; ji < UPW; ++ji) red[wave * 32 + lane * 8 + ji] = acc[ji];
        }

        // fc partials for out[s-1] (rotating WG; rides barrier (a))
        if (rot) {
            float po0 = 0.0f, po1 = 0.0f;
            #pragma unroll
            for (int k = 0; k < CPT; ++k) {
                po0 += hr[k] * W_fc[col0 + k];
                po1 += hr[k] * W_fc[HIDDEN + col0 + k];
            }
            #pragma unroll
            for (int m = 1; m < 64; m <<= 1) {
                po0 += __shfl_xor(po0, m);
                po1 += __shfl_xor(po1, m);
            }
            if (lane == 0) { outred[wave * 2 + 0] = po0; outred[wave * 2 + 1] = po1; }
        }
        __syncthreads();   // (a) red[] + outred[] ready

        if (wave == 0) {
            // final reduce + gates + publish (v6-identical)
            const int l = lane & 31;
            float sum = 0.0f;
            #pragma unroll
            for (int ww = 0; ww < 8; ++ww) sum += red[ww * 32 + l];
            const float x0 = pc_sh[2 * s], x1 = pc_sh[2 * s + 1];
            const float gate = sum + bias_r + wi0_r * x0 + wi1_r * x1;
            const float iv = __shfl(gate, (lane & 7));
            const float fv = __shfl(gate, 8 + (lane & 7));
            const float gv = __shfl(gate, 16 + (lane & 7));
            const float ov = __shfl(gate, 24 + (lane & 7));
            const float cnew = sigmoidf_(fv) * creg + sigmoidf_(iv) * tanhf(gv);
            const float hnew = sigmoidf_(ov) * tanhf(cnew);
            creg = cnew;   // lane tracks unit lane&7
            const uint32_t hb = __float_as_uint(hnew);

            // publish 8 floats as 4 write-through qword stores
            const uint32_t lo = __shfl(hb, 2 * (lane & 3));
            const uint32_t hi = __shfl(hb, 2 * (lane & 3) + 1);
            if (lane < 4) {
                const uint64_t qv = (uint64_t)lo | ((uint64_t)hi << 32);
                uint64_t* dst = reinterpret_cast<uint64_t*>(
                    hhist + (size_t)(s + 1) * HIDDEN + b * UPW) + lane;
                __hip_atomic_store(dst, qv, __ATOMIC_RELAXED, __HIP_MEMORY_SCOPE_AGENT);
            }
            // data acked at the coherence point before the flag becomes visible
            asm volatile("s_waitcnt vmcnt(0)" ::: "memory");
            if (lane == 0) {
                __hip_atomic_store(flags + (size_t)b * FLAG_STRIDE, s + 1,
                                   __ATOMIC_RELAXED, __HIP_MEMORY_SCOPE_AGENT);
            }
        }

        // watcher: WG 255 wave 7 — starts at (a), overlaps all gate compute
        if (isw255 && wave == 7) {
            const int l4 = lane * 4;
            const int* f0p = flags + (size_t)(l4 + 0) * FLAG_STRIDE;
            const int* f1p = flags + (size_t)(l4 + 1) * FLAG_STRIDE;
            const int* f2p = flags + (size_t)(l4 + 2) * FLAG_STRIDE;
            const int* f3p = flags + (size_t)(l4 + 3) * FLAG_STRIDE;
            for (;;) {
                const int f0 = __hip_atomic_load(f0p, __ATOMIC_RELAXED, __HIP_MEMORY_SCOPE_AGENT);
                const int f1 = __hip_atomic_load(f1p, __ATOMIC_RELAXED, __HIP_MEMORY_SCOPE_AGENT);
                const int f2 = __hip_atomic_load(f2p, __ATOMIC_RELAXED, __HIP_MEMORY_SCOPE_AGENT);
                const int f3 = __hip_atomic_load(f3p, __ATOMIC_RELAXED, __HIP_MEMORY_SCOPE_AGENT);
                const bool ok = (f0 >= s + 1) & (f1 >= s + 1) & (f2 >= s + 1) & (f3 >= s + 1);
                if (__all(ok)) break;
            }
            // fan-out: 64 agent go lines + LDS self-gate
            __hip_atomic_store(go + (size_t)lane * GO_STRIDE, s + 1,
                               __ATOMIC_RELAXED, __HIP_MEMORY_SCOPE_AGENT);
            if (lane == 0) {
                __hip_atomic_store(&ls_go, s + 1, __ATOMIC_RELAXED,
                                   __HIP_MEMORY_SCOPE_WORKGROUP);
            }
        }

        // out[s-1] final sum (outred valid since (a))
        if (rot && t == 64) {
            float o0 = 0.0f, o1 = 0.0f;
            #pragma unroll
            for (int ww = 0; ww < 8; ++ww) { o0 += outred[ww * 2]; o1 += outred[ww * 2 + 1]; }
            out[(s - 1) * 2 + 0] = 0.25f * o0 + b_fc[0];
            out[(s - 1) * 2 + 1] = 0.25f * o1 + b_fc[1];
        }
        // no barrier (b): the go-gate at the top of the next iteration orders
        // everything (red[] writes at s+1 causally follow wave 0's red[] read at s).
    }

    // ---- epilogue: out[T-1] = fc(h_T); (T-1)&255 = 255 -> WG 255 ----
    if (isw255) {
        while (__hip_atomic_load(&ls_go, __ATOMIC_RELAXED,
                                 __HIP_MEMORY_SCOPE_WORKGROUP) < TSTEPS) {}
        const float* hsrc = hhist + (size_t)TSTEPS * HIDDEN;
        float po0 = 0.0f, po1 = 0.0f;
        #pragma unroll
        for (int k = 0; k < CPT; ++k) {
            const float hv = hsrc[col0 + k];
            po0 += hv * W_fc[col0 + k];
            po1 += hv * W_fc[HIDDEN + col0 + k];
        }
        #pragma unroll
        for (int m = 1; m < 64; m <<= 1) {
            po0 += __shfl_xor(po0, m);
            po1 += __shfl_xor(po1, m);
        }
        if (lane == 0) { outred[wave * 2 + 0] = po0; outred[wave * 2 + 1] = po1; }
        __syncthreads();
        if (t == 0) {
            float o0 = 0.0f, o1 = 0.0f;
            #pragma unroll
            for (int ww = 0; ww < 8; ++ww) { o0 += outred[ww * 2]; o1 += outred[ww * 2 + 1]; }
            out[(TSTEPS - 1) * 2 + 0] = 0.25f * o0 + b_fc[0];
            out[(TSTEPS - 1) * 2 + 1] = 0.25f * o1 + b_fc[1];
        }
    }
}

extern "C" void kernel_launch(void* const* d_in, const int* in_sizes, int n_in,
                              void* d_out, int out_size, void* d_ws, size_t ws_size,
                              hipStream_t stream) {
    const float* features = (const float*)d_in[0];
    const float* pc       = (const float*)d_in[1];
    const float* W_ih     = (const float*)d_in[2];
    const float* W_hh     = (const float*)d_in[3];
    const float* b_ih     = (const float*)d_in[4];
    const float* b_hh     = (const float*)d_in[5];
    const float* W_fc     = (const float*)d_in[6];
    const float* b_fc     = (const float*)d_in[7];
    float* out = (float*)d_out;

    const size_t flags_bytes = (size_t)NWG * FLAG_STRIDE * sizeof(int);  // 32 KB
    const size_t go_bytes    = (size_t)64 * GO_STRIDE * sizeof(int);     //  8 KB
    const size_t hh_off      = flags_bytes + go_bytes;                   // 40 KB (256B-aligned)

    int*   flags = (int*)d_ws;
    int*   go    = (int*)((char*)d_ws + flags_bytes);
    float* hhist = (float*)((char*)d_ws + hh_off);

    // flags/go must start at 0 every call (graph replays don't re-poison ws)
    hipMemsetAsync(d_ws, 0, hh_off, stream);

    hipLaunchKernelGGL(lstm_v10, dim3(NWG), dim3(TPB), 0, stream,
                       features, pc, W_ih, W_hh, b_ih, b_hh, W_fc, b_fc,
                       out, flags, go, hhist);
}